// Round 1
// baseline (2958.153 us; speedup 1.0000x reference)
//
#include <hip/hip_runtime.h>

// BinaryTreeLSTM — round 7: single persistent mega-kernel for all 18 levels.
//  * One dispatch: kills ~12 launch gaps, B-slice LDS DMA done ONCE per block
//    (by fixed per block for the whole kernel), biases register-resident.
//  * emb_cvt pre-pass removed: A-prefetch reads fp32 emb directly and converts
//    in-register (identical rounding; saves 192 MB traffic + one launch).
//  * Grid barrier between levels: two-level (8 groups x 96) monotonic atomic
//    counters, poison-tolerant MAGIC handshake (ws re-poisoned each launch).
//  * bid mapping: by = bid/96, stream = bid%96 -> the 8 by-siblings sharing an
//    A tile are bids = by*96+s, identical mod 8 -> same XCD L2 (96%8==0).
//  * 768 blocks = 256 CU x 3 (48 KB LDS, __launch_bounds__(256,3)) ->
//    co-residency guaranteed by capacity; A-ring depth 2 to fit 170 VGPRs.

typedef _Float16 f16;
typedef f16 f16x8 __attribute__((ext_vector_type(8)));
typedef float f32x4 __attribute__((ext_vector_type(4)));

#define MAGIC 0xC0FFEEu
#define LOG2E 1.44269504f
#define STREAMS 96   // grid = 8 * STREAMS = 768 blocks = 3/CU

__device__ __forceinline__ float sigf(float x) {
    return __builtin_amdgcn_rcpf(1.f + __builtin_amdgcn_exp2f(-x * LOG2E));
}
__device__ __forceinline__ float tanh_fast(float x) {
    return 1.f - 2.f * __builtin_amdgcn_rcpf(1.f + __builtin_amdgcn_exp2f(2.f * x * LOG2E));
}

__device__ __forceinline__ void load_lds_16(const void* g, void* l) {
    __builtin_amdgcn_global_load_lds(
        (const __attribute__((address_space(1))) unsigned int*)g,
        (__attribute__((address_space(3))) unsigned int*)l, 16, 0, 0);
}

// Bp layout: [by(8)][kci(12)][kq(4)][c(64)][k8(8)] fp16, c = g*16 + jl,
// orig row = g*256 + by*16 + jl, orig k = kci*32 + kq*8 + k8.
__global__ __launch_bounds__(256) void pack_weights(
    const float* __restrict__ W_ih, const float* __restrict__ W_hh,
    const float* __restrict__ b_ih, const float* __restrict__ b_hh,
    f16* __restrict__ Bp, float* __restrict__ biasP)
{
    int idx = blockIdx.x * 256 + threadIdx.x;
    if (idx < 196608) {
        int by = idx / 24576;
        int r = idx - by * 24576;
        int kci = r / 2048;
        int r2 = r & 2047;
        int kq = r2 >> 9;
        int r3 = r2 & 511;
        int c = r3 >> 3;
        int k8 = r3 & 7;
        int g = c >> 4, jl = c & 15;
        int rOrig = g * 256 + by * 16 + jl;
        int kk = kci * 32 + kq * 8 + k8;
        float w = (kk < 128) ? W_ih[(size_t)rOrig * 128 + kk]
                             : W_hh[(size_t)rOrig * 256 + (kk - 128)];
        Bp[idx] = (f16)w;
    }
    if (idx < 512) {
        int by = idx >> 6, c = idx & 63;
        int g = c >> 4, jl = c & 15;
        int rOrig = g * 256 + by * 16 + jl;
        biasP[idx] = b_ih[rOrig] + b_hh[rOrig];
    }
}

// One A fragment: 8 fp16 of row `row`, k = kci*32 + kq*8 .. +8.
// kci < 4 -> fp32 embeddings converted in-register; kci >= 4 -> fp16 h_in.
// kci is compile-time constant at every call site (fully unrolled loops).
__device__ __forceinline__ f16x8 loadA2(
    const float* __restrict__ emb, const f16* __restrict__ h_in,
    int n, int row, int kci, int kq)
{
    f16x8 r;
    if (kci < 4) {
        const float4* p = (const float4*)(emb + (size_t)(n - 1 + row) * 128 + kci * 32 + kq * 8);
        float4 a = p[0], b = p[1];
        r[0] = (f16)a.x; r[1] = (f16)a.y; r[2] = (f16)a.z; r[3] = (f16)a.w;
        r[4] = (f16)b.x; r[5] = (f16)b.y; r[6] = (f16)b.z; r[7] = (f16)b.w;
    } else {
        r = *(const f16x8*)(h_in + (size_t)row * 256 + (kci - 4) * 32 + kq * 8);
    }
    return r;
}

template <int NCH>
__device__ __forceinline__ void tile_compute(
    const float* __restrict__ emb, const f16* __restrict__ Bs,
    int n, int row0, int l15, int kq, int j,
    float bi, float bfv, float bg, float bo,
    const f16* __restrict__ h_in, const float* __restrict__ c_in,
    f16* __restrict__ h_out, float* __restrict__ c_out,
    float* __restrict__ root_out)
{
    f32x4 acc[4][4];
    #pragma unroll
    for (int a = 0; a < 4; ++a)
        #pragma unroll
        for (int b = 0; b < 4; ++b) acc[a][b] = (f32x4)0.f;

    int rowm[4];
    #pragma unroll
    for (int mi = 0; mi < 4; ++mi) {
        int rr = row0 + mi * 16 + l15;
        rowm[mi] = (rr < n) ? rr : (n - 1);
    }

    // depth-2 prefetch ring (12 waves/CU hide the rest at wave level)
    f16x8 af[2][4];
    #pragma unroll
    for (int pk = 0; pk < 2; ++pk) {
        if (pk < NCH) {
            #pragma unroll
            for (int mi = 0; mi < 4; ++mi)
                af[pk][mi] = loadA2(emb, h_in, n, rowm[mi], pk, kq);
        }
    }

    #pragma unroll
    for (int kci = 0; kci < NCH; ++kci) {
        const int sl = kci & 1;
        f16x8 bf[4];
        #pragma unroll
        for (int g = 0; g < 4; ++g)
            bf[g] = *(const f16x8*)&Bs[((kci * 4 + kq) * 64 + g * 16 + l15) * 8];
        f16x8 a0 = af[sl][0], a1 = af[sl][1], a2 = af[sl][2], a3 = af[sl][3];
        if (kci + 2 < NCH) {
            #pragma unroll
            for (int mi = 0; mi < 4; ++mi)
                af[sl][mi] = loadA2(emb, h_in, n, rowm[mi], kci + 2, kq);
        }
        #pragma unroll
        for (int g = 0; g < 4; ++g) {
            acc[0][g] = __builtin_amdgcn_mfma_f32_16x16x32_f16(a0, bf[g], acc[0][g], 0, 0, 0);
            acc[1][g] = __builtin_amdgcn_mfma_f32_16x16x32_f16(a1, bf[g], acc[1][g], 0, 0, 0);
            acc[2][g] = __builtin_amdgcn_mfma_f32_16x16x32_f16(a2, bf[g], acc[2][g], 0, 0, 0);
            acc[3][g] = __builtin_amdgcn_mfma_f32_16x16x32_f16(a3, bf[g], acc[3][g], 0, 0, 0);
        }
    }

    #pragma unroll
    for (int mi = 0; mi < 4; ++mi) {
        #pragma unroll
        for (int r = 0; r < 4; ++r) {
            int row = row0 + mi * 16 + kq * 4 + r;
            if (row < n) {
                float gi = acc[mi][0][r] + bi;
                float gf = acc[mi][1][r] + bfv;
                float gg = acc[mi][2][r] + bg;
                float go = acc[mi][3][r] + bo;
                float cl = (NCH == 4) ? 0.f : c_in[(size_t)row * 128 + j];
                float cn = sigf(gf) * cl + sigf(gi) * tanh_fast(gg);
                float hn = sigf(go) * tanh_fast(cn);
                if (root_out) {
                    root_out[j] = hn;
                    root_out[128 + j] = cn;
                } else {
                    h_out[(size_t)row * 128 + j] = (f16)hn;
                    if (!(row & 1))
                        c_out[(size_t)(row >> 1) * 128 + j] = cn;
                }
            }
        }
    }
}

// Two-level grid barrier: 8 group counters (128 B apart) + 1 global.
// Monotonic counts, poison-tolerant via MAGIC handshake at kernel start.
__device__ __forceinline__ void grid_bar768(unsigned* sync, int grp, unsigned phase) {
    __syncthreads();
    if (threadIdx.x == 0) {
        __threadfence();
        unsigned old = __hip_atomic_fetch_add(&sync[grp * 32], 1u,
                                              __ATOMIC_ACQ_REL, __HIP_MEMORY_SCOPE_AGENT);
        if (old == phase * (unsigned)STREAMS - 1u)
            __hip_atomic_fetch_add(&sync[256], 1u,
                                   __ATOMIC_ACQ_REL, __HIP_MEMORY_SCOPE_AGENT);
        while (__hip_atomic_load(&sync[256], __ATOMIC_ACQUIRE,
                                 __HIP_MEMORY_SCOPE_AGENT) < phase * 8u)
            __builtin_amdgcn_s_sleep(8);
        __threadfence();
    }
    __syncthreads();
}

__global__ __launch_bounds__(256, 3) void mega(
    const float* __restrict__ emb,
    const f16* __restrict__ Bp, const float* __restrict__ biasP,
    f16* __restrict__ hA, float* __restrict__ cA,
    f16* __restrict__ hB, float* __restrict__ cB,
    float* __restrict__ root_out, unsigned* __restrict__ sync)
{
    __shared__ __align__(16) f16 Bs[24576];   // 48 KB -> 3 blocks/CU

    const int tid = threadIdx.x;
    const int lane = tid & 63;
    const int w = tid >> 6;
    const int l15 = lane & 15;
    const int kq = lane >> 4;

    const int bid = blockIdx.x;
    const int by = bid / STREAMS;     // fixed weight slice for whole kernel
    const int s = bid % STREAMS;      // rb stream; siblings same XCD (96%8==0)

    {   // B slice -> LDS exactly once for all 18 levels
        const char* gB = (const char*)(Bp + (size_t)by * 24576);
        char* lB = (char*)Bs;
        #pragma unroll
        for (int i = 0; i < 12; ++i)
            load_lds_16(gB + ((size_t)(i * 256 + tid)) * 16,
                        lB + ((size_t)(i * 256 + w * 64)) * 16);
    }

    // Poison-tolerant init handshake (ws is re-poisoned 0xAA each launch)
    if (bid == 0 && tid == 0) {
        #pragma unroll
        for (int g = 0; g < 8; ++g)
            __hip_atomic_store(&sync[g * 32], 0u, __ATOMIC_RELAXED, __HIP_MEMORY_SCOPE_AGENT);
        __hip_atomic_store(&sync[256], 0u, __ATOMIC_RELAXED, __HIP_MEMORY_SCOPE_AGENT);
        __hip_atomic_store(&sync[257], MAGIC, __ATOMIC_RELEASE, __HIP_MEMORY_SCOPE_AGENT);
    }
    if (tid == 0) {
        while (__hip_atomic_load(&sync[257], __ATOMIC_ACQUIRE,
                                 __HIP_MEMORY_SCOPE_AGENT) != MAGIC)
            __builtin_amdgcn_s_sleep(8);
    }
    __syncthreads();   // B resident + counters initialized

    const int j = by * 16 + l15;
    const float bi = biasP[by * 64 + 0 + l15];
    const float bfv = biasP[by * 64 + 16 + l15];
    const float bg = biasP[by * 64 + 32 + l15];
    const float bo = biasP[by * 64 + 48 + l15];

    f16* hp[2] = { hA, hB };
    float* cp[2] = { cA, cB };
    int p = 0;
    unsigned phase = 0;

    for (int d = 17; d >= 0; --d) {
        const int n = 1 << d;
        const int R = (n >= 256) ? (n >> 8) : 1;
        const f16* h_in = hp[p ^ 1];
        const float* c_in = cp[p ^ 1];
        f16* h_out = hp[p];
        float* c_out = cp[p];
        float* root = (d == 0) ? root_out : nullptr;

        for (int t = s; t < R; t += STREAMS) {
            const int row0 = t * 256 + w * 64;
            if (d == 17)
                tile_compute<4>(emb, Bs, n, row0, l15, kq, j, bi, bfv, bg, bo,
                                h_in, c_in, h_out, c_out, nullptr);
            else
                tile_compute<12>(emb, Bs, n, row0, l15, kq, j, bi, bfv, bg, bo,
                                 h_in, c_in, h_out, c_out, root);
        }

        if (d > 0) {
            ++phase;
            grid_bar768(sync, bid & 7, phase);
        }
        p ^= 1;
    }
}

extern "C" void kernel_launch(void* const* d_in, const int* in_sizes, int n_in,
                              void* d_out, int out_size, void* d_ws, size_t ws_size,
                              hipStream_t stream) {
    const float* emb  = (const float*)d_in[0];
    const float* W_ih = (const float*)d_in[1];
    const float* W_hh = (const float*)d_in[2];
    const float* b_ih = (const float*)d_in[3];
    const float* b_hh = (const float*)d_in[4];

    char* wsb = (char*)d_ws;
    f16*   Bp    = (f16*)wsb;                      // 393216 B
    float* biasP = (float*)(wsb + 393216);         // 2048 B
    unsigned* syncp = (unsigned*)(wsb + 397312);   // 8 groups*128B + global + magic
    const size_t HBUF = (size_t)131072 * 128 * sizeof(f16);   // 32 MiB
    const size_t CBUF = (size_t)65536 * 128 * sizeof(float);  // 32 MiB (packed)
    char* bufs = wsb + 1048576;
    f16* hbuf[2]   = { (f16*)bufs, (f16*)(bufs + HBUF) };
    float* cbuf[2] = { (float*)(bufs + 2 * HBUF), (float*)(bufs + 2 * HBUF + CBUF) };
    if (ws_size < 1048576 + 2 * HBUF + 2 * CBUF) return;

    pack_weights<<<768, 256, 0, stream>>>(W_ih, W_hh, b_ih, b_hh, Bp, biasP);
    mega<<<768, 256, 0, stream>>>(emb, Bp, biasP,
        hbuf[0], cbuf[0], hbuf[1], cbuf[1], (float*)d_out, syncp);
}

// Round 2
// 890.386 us; speedup vs baseline: 3.3223x; 3.3223x over previous
//
#include <hip/hip_runtime.h>

// BinaryTreeLSTM — round 8: persistent mega-kernel with XCD-LOCAL dataflow.
//  * Round-7 post-mortem: 2866us with MfmaUtil 0.96% => 99% stall. Cause:
//    __threadfence() per block per barrier = buffer_wbl2/buffer_inv sc1
//    (full L2 writeback+invalidate) x 26k => L2 thrash, latency-bound.
//  * Tree is XCD-partitionable: XCD x owns rows [x*n/8,(x+1)*n/8) at EVERY
//    level; children stay in-chunk => levels d=17..3 need NO cross-XCD data.
//    Within an XCD: release = vmcnt drain (done by __syncthreads before
//    barrier arrival), acquire = buffer_inv sc0 (L1-only, cheap). No L2 ops.
//  * Physical XCD discovered via s_getreg(HW_REG_XCC_ID); blocks take an
//    atomic ticket per XCD => rank/by/stream robust to any dispatch order.
//  * Barriers: hierarchical agent-scope counters (RMW arrive on per-XCD
//    line, load-poll a single global word). All sync at coherence point.
//  * Per-LEVEL h/c buffers (no ping-pong reuse): every address written once
//    by one XCD => no stale-dirty-line writeback races, no L1 aliasing.
//  * d=3 -> d<=2 hand-off: 8 rank-0 blocks publish via ONE __threadfence()
//    each; 8 blocks on XCD0 (rank<8, by=rank) compute d=2..0 and the root.

typedef _Float16 f16;
typedef f16 f16x8 __attribute__((ext_vector_type(8)));
typedef float f32x4 __attribute__((ext_vector_type(4)));

#define MAGIC 0xC0FFEEu
#define LOG2E 1.44269504f

// sync[] indices (unsigned units); lines 128B apart where contended
#define GCNT(x)  ((x) * 32)       // per-XCD ticket counters
#define TOTALI   256
#define MAGICI   257
#define DONEI    258
#define XARR(x)  (320 + (x) * 32) // per-XCD barrier arrival counters
#define GBARI    576              // global phase counter (8 per phase)
#define FBARI    608              // finals barrier (XCD0 only)

__device__ __forceinline__ float sigf(float x) {
    return __builtin_amdgcn_rcpf(1.f + __builtin_amdgcn_exp2f(-x * LOG2E));
}
__device__ __forceinline__ float tanh_fast(float x) {
    return 1.f - 2.f * __builtin_amdgcn_rcpf(1.f + __builtin_amdgcn_exp2f(2.f * x * LOG2E));
}

__device__ __forceinline__ void load_lds_16(const void* g, void* l) {
    __builtin_amdgcn_global_load_lds(
        (const __attribute__((address_space(1))) unsigned int*)g,
        (__attribute__((address_space(3))) unsigned int*)l, 16, 0, 0);
}

// Bp layout: [by(8)][kci(12)][kq(4)][c(64)][k8(8)] fp16, c = g*16 + jl,
// orig row = g*256 + by*16 + jl, orig k = kci*32 + kq*8 + k8.
__global__ __launch_bounds__(256) void pack_weights(
    const float* __restrict__ W_ih, const float* __restrict__ W_hh,
    const float* __restrict__ b_ih, const float* __restrict__ b_hh,
    f16* __restrict__ Bp, float* __restrict__ biasP)
{
    int idx = blockIdx.x * 256 + threadIdx.x;
    if (idx < 196608) {
        int by = idx / 24576;
        int r = idx - by * 24576;
        int kci = r / 2048;
        int r2 = r & 2047;
        int kq = r2 >> 9;
        int r3 = r2 & 511;
        int c = r3 >> 3;
        int k8 = r3 & 7;
        int g = c >> 4, jl = c & 15;
        int rOrig = g * 256 + by * 16 + jl;
        int kk = kci * 32 + kq * 8 + k8;
        float w = (kk < 128) ? W_ih[(size_t)rOrig * 128 + kk]
                             : W_hh[(size_t)rOrig * 256 + (kk - 128)];
        Bp[idx] = (f16)w;
    }
    if (idx < 512) {
        int by = idx >> 6, c = idx & 63;
        int g = c >> 4, jl = c & 15;
        int rOrig = g * 256 + by * 16 + jl;
        biasP[idx] = b_ih[rOrig] + b_hh[rOrig];
    }
}

// Per-level buffers: level d's h is (2^d rows,128) f16 = 2^d*256 B;
// c packed (2^(d-1) rows,128) f32 = 2^d*256 B. offset(d)=256*(2^18-2^(d+1)).
__device__ __forceinline__ f16* hLvl(char* H, int d) {
    return (f16*)(H + (size_t)256u * ((1u << 18) - (1u << (d + 1))));
}
__device__ __forceinline__ float* cLvl(char* C, int d) {
    return (float*)(C + (size_t)256u * ((1u << 18) - (1u << (d + 1))));
}

// One A fragment: 8 fp16 of row `row`, k = kci*32 + kq*8 .. +8.
// kci < 4 -> fp32 embeddings converted in-register; kci >= 4 -> fp16 h_in.
__device__ __forceinline__ f16x8 loadA2(
    const float* __restrict__ emb, const f16* __restrict__ h_in,
    int n, int row, int kci, int kq)
{
    f16x8 r;
    if (kci < 4) {
        const float4* p = (const float4*)(emb + (size_t)(n - 1 + row) * 128 + kci * 32 + kq * 8);
        float4 a = p[0], b = p[1];
        r[0] = (f16)a.x; r[1] = (f16)a.y; r[2] = (f16)a.z; r[3] = (f16)a.w;
        r[4] = (f16)b.x; r[5] = (f16)b.y; r[6] = (f16)b.z; r[7] = (f16)b.w;
    } else {
        r = *(const f16x8*)(h_in + (size_t)row * 256 + (kci - 4) * 32 + kq * 8);
    }
    return r;
}

template <int NCH, int CLAMP>
__device__ __forceinline__ void tile_compute(
    const float* __restrict__ emb, const f16* __restrict__ Bs,
    int n, int row0, int rlimit, int l15, int kq, int j,
    float bi, float bfv, float bg, float bo,
    const f16* __restrict__ h_in, const float* __restrict__ c_in,
    f16* __restrict__ h_out, float* __restrict__ c_out,
    float* __restrict__ root_out)
{
    f32x4 acc[4][4];
    #pragma unroll
    for (int a = 0; a < 4; ++a)
        #pragma unroll
        for (int b = 0; b < 4; ++b) acc[a][b] = (f32x4)0.f;

    int rowm[4];
    #pragma unroll
    for (int mi = 0; mi < 4; ++mi) {
        int rr = row0 + mi * 16 + l15;
        rowm[mi] = CLAMP ? ((rr < rlimit) ? rr : (rlimit - 1)) : rr;
    }

    // depth-2 prefetch ring (12 waves/CU hide the rest at wave level)
    f16x8 af[2][4];
    #pragma unroll
    for (int pk = 0; pk < 2; ++pk) {
        if (pk < NCH) {
            #pragma unroll
            for (int mi = 0; mi < 4; ++mi)
                af[pk][mi] = loadA2(emb, h_in, n, rowm[mi], pk, kq);
        }
    }

    #pragma unroll
    for (int kci = 0; kci < NCH; ++kci) {
        const int sl = kci & 1;
        f16x8 bf[4];
        #pragma unroll
        for (int g = 0; g < 4; ++g)
            bf[g] = *(const f16x8*)&Bs[((kci * 4 + kq) * 64 + g * 16 + l15) * 8];
        f16x8 a0 = af[sl][0], a1 = af[sl][1], a2 = af[sl][2], a3 = af[sl][3];
        if (kci + 2 < NCH) {
            #pragma unroll
            for (int mi = 0; mi < 4; ++mi)
                af[sl][mi] = loadA2(emb, h_in, n, rowm[mi], kci + 2, kq);
        }
        #pragma unroll
        for (int g = 0; g < 4; ++g) {
            acc[0][g] = __builtin_amdgcn_mfma_f32_16x16x32_f16(a0, bf[g], acc[0][g], 0, 0, 0);
            acc[1][g] = __builtin_amdgcn_mfma_f32_16x16x32_f16(a1, bf[g], acc[1][g], 0, 0, 0);
            acc[2][g] = __builtin_amdgcn_mfma_f32_16x16x32_f16(a2, bf[g], acc[2][g], 0, 0, 0);
            acc[3][g] = __builtin_amdgcn_mfma_f32_16x16x32_f16(a3, bf[g], acc[3][g], 0, 0, 0);
        }
    }

    #pragma unroll
    for (int mi = 0; mi < 4; ++mi) {
        #pragma unroll
        for (int r = 0; r < 4; ++r) {
            int row = row0 + mi * 16 + kq * 4 + r;
            if (!CLAMP || row < rlimit) {
                float gi = acc[mi][0][r] + bi;
                float gf = acc[mi][1][r] + bfv;
                float gg = acc[mi][2][r] + bg;
                float go = acc[mi][3][r] + bo;
                float cl = (NCH == 4) ? 0.f : c_in[(size_t)row * 128 + j];
                float cn = sigf(gf) * cl + sigf(gi) * tanh_fast(gg);
                float hn = sigf(go) * tanh_fast(cn);
                if (root_out) {
                    root_out[j] = hn;
                    root_out[128 + j] = cn;
                } else {
                    h_out[(size_t)row * 128 + j] = (f16)hn;
                    if (!(row & 1))
                        c_out[(size_t)(row >> 1) * 128 + j] = cn;
                }
            }
        }
    }
}

// Hierarchical grid barrier, all counters agent-scope (coherence point).
// Arrive: RMW on per-XCD line; last arriver bumps GBAR; release: load-poll
// GBAR (loads, not RMWs -> no serialization). Acquire for XCD-local data =
// L1 invalidate only (L2 is the intra-XCD coherence point; L1 write-through).
__device__ __forceinline__ void gbar(unsigned* sync, unsigned xcc,
                                     unsigned phase, unsigned Gx) {
    __syncthreads();   // per-wave vmcnt drain: all block stores are in L2
    if (threadIdx.x == 0) {
        unsigned old = __hip_atomic_fetch_add(&sync[XARR(xcc)], 1u,
                                              __ATOMIC_RELAXED, __HIP_MEMORY_SCOPE_AGENT);
        if (old == phase * Gx - 1u)
            __hip_atomic_fetch_add(&sync[GBARI], 1u,
                                   __ATOMIC_RELAXED, __HIP_MEMORY_SCOPE_AGENT);
        while (__hip_atomic_load(&sync[GBARI], __ATOMIC_RELAXED,
                                 __HIP_MEMORY_SCOPE_AGENT) < phase * 8u)
            __builtin_amdgcn_s_sleep(8);
        asm volatile("buffer_inv sc0" ::: "memory");   // L1-only invalidate
    }
    __syncthreads();
}

__global__ __launch_bounds__(256, 3) void mega(
    const float* __restrict__ emb,
    const f16* __restrict__ Bp, const float* __restrict__ biasP,
    char* __restrict__ H, char* __restrict__ C,
    float* __restrict__ root_out, unsigned* __restrict__ sync)
{
    __shared__ __align__(16) f16 Bs[24576];   // 48 KB -> 3 blocks/CU
    __shared__ unsigned meta[2];

    const int tid = threadIdx.x;
    const int lane = tid & 63;
    const int w = tid >> 6;
    const int l15 = lane & 15;
    const int kq = lane >> 4;

    unsigned xcc;
    asm volatile("s_getreg_b32 %0, hwreg(HW_REG_XCC_ID)" : "=s"(xcc));
    xcc &= 7u;

    // ---- init (poison-tolerant) + XCD ticket + global count ----
    if (blockIdx.x == 0 && tid == 0) {
        for (int x = 0; x < 8; ++x) {
            __hip_atomic_store(&sync[GCNT(x)], 0u, __ATOMIC_RELAXED, __HIP_MEMORY_SCOPE_AGENT);
            __hip_atomic_store(&sync[XARR(x)], 0u, __ATOMIC_RELAXED, __HIP_MEMORY_SCOPE_AGENT);
        }
        __hip_atomic_store(&sync[TOTALI], 0u, __ATOMIC_RELAXED, __HIP_MEMORY_SCOPE_AGENT);
        __hip_atomic_store(&sync[DONEI], 0u, __ATOMIC_RELAXED, __HIP_MEMORY_SCOPE_AGENT);
        __hip_atomic_store(&sync[GBARI], 0u, __ATOMIC_RELAXED, __HIP_MEMORY_SCOPE_AGENT);
        __hip_atomic_store(&sync[FBARI], 0u, __ATOMIC_RELAXED, __HIP_MEMORY_SCOPE_AGENT);
        __hip_atomic_store(&sync[MAGICI], MAGIC, __ATOMIC_RELEASE, __HIP_MEMORY_SCOPE_AGENT);
    }
    if (tid == 0) {
        while (__hip_atomic_load(&sync[MAGICI], __ATOMIC_RELAXED,
                                 __HIP_MEMORY_SCOPE_AGENT) != MAGIC)
            __builtin_amdgcn_s_sleep(32);
        unsigned r = __hip_atomic_fetch_add(&sync[GCNT(xcc)], 1u,
                                            __ATOMIC_RELAXED, __HIP_MEMORY_SCOPE_AGENT);
        asm volatile("s_waitcnt vmcnt(0)" ::: "memory");  // ticket visible before count
        __hip_atomic_fetch_add(&sync[TOTALI], 1u,
                               __ATOMIC_RELAXED, __HIP_MEMORY_SCOPE_AGENT);
        while (__hip_atomic_load(&sync[TOTALI], __ATOMIC_RELAXED,
                                 __HIP_MEMORY_SCOPE_AGENT) < 768u)
            __builtin_amdgcn_s_sleep(32);
        meta[0] = r;
        meta[1] = __hip_atomic_load(&sync[GCNT(xcc)], __ATOMIC_RELAXED,
                                    __HIP_MEMORY_SCOPE_AGENT);
    }
    __syncthreads();
    const unsigned rank = meta[0];
    const unsigned Gx = meta[1];             // exact blocks on this XCD
    const int by = (int)(rank & 7u);         // weight slice for whole kernel
    const int strm = (int)(rank >> 3);       // stream within (xcd, by)
    const int nstr = (int)((Gx - (unsigned)by + 7u) >> 3);

    {   // B slice -> LDS exactly once for all levels
        const char* gB = (const char*)(Bp + (size_t)by * 24576);
        char* lB = (char*)Bs;
        #pragma unroll
        for (int i = 0; i < 12; ++i)
            load_lds_16(gB + ((size_t)(i * 256 + tid)) * 16,
                        lB + ((size_t)(i * 256 + w * 64)) * 16);
    }
    __syncthreads();   // drain DMA

    const int j = by * 16 + l15;
    const float bi = biasP[by * 64 + 0 + l15];
    const float bfv = biasP[by * 64 + 16 + l15];
    const float bg = biasP[by * 64 + 32 + l15];
    const float bo = biasP[by * 64 + 48 + l15];

    // ---- XCD-local levels d=17..3 ----
    unsigned phase = 0;
    for (int d = 17; d >= 3; --d) {
        const int n = 1 << d;
        const int chunk = n >> 3;            // rows owned by this XCD
        const int base = (int)xcc * chunk;
        const f16* h_in = hLvl(H, d + 1 < 18 ? d + 1 : 17);  // d=17: unused
        const float* c_in = cLvl(C, d + 1 < 18 ? d + 1 : 17);
        f16* h_out = hLvl(H, d);
        float* c_out = cLvl(C, d);

        if (d == 17) {
            for (int t = strm; t < 64; t += nstr) {
                int row0 = base + t * 256 + w * 64;
                tile_compute<4, 0>(emb, Bs, n, row0, 0, l15, kq, j,
                                   bi, bfv, bg, bo, h_in, c_in, h_out, c_out, nullptr);
            }
        } else if (d >= 11) {
            const int T = 1 << (d - 11);     // full 256-row tiles in chunk
            for (int t = strm; t < T; t += nstr) {
                int row0 = base + t * 256 + w * 64;
                tile_compute<12, 0>(emb, Bs, n, row0, 0, l15, kq, j,
                                    bi, bfv, bg, bo, h_in, c_in, h_out, c_out, nullptr);
            }
        } else {
            if (strm == 0 && w * 64 < chunk) {
                int row0 = base + w * 64;
                tile_compute<12, 1>(emb, Bs, n, row0, base + chunk, l15, kq, j,
                                    bi, bfv, bg, bo, h_in, c_in, h_out, c_out, nullptr);
            }
        }

        ++phase;
        gbar(sync, xcc, phase, Gx);
    }

    // ---- publish d=3 results cross-XCD (8 threadfences total) ----
    if (rank == 0 && tid == 0) {
        __threadfence();   // wb local L2 (holds this XCD's d=3 rows) + inv
        __hip_atomic_fetch_add(&sync[DONEI], 1u,
                               __ATOMIC_RELAXED, __HIP_MEMORY_SCOPE_AGENT);
    }

    const bool fin = (xcc == 0u) && (rank < 8u);   // by = rank, distinct
    if (!fin) return;

    if (tid == 0) {
        while (__hip_atomic_load(&sync[DONEI], __ATOMIC_RELAXED,
                                 __HIP_MEMORY_SCOPE_AGENT) < 8u)
            __builtin_amdgcn_s_sleep(16);
        __threadfence();   // acquire: invalidate local L1+L2
    }
    __syncthreads();

    // ---- finals: d=2,1,0 on 8 XCD0 blocks ----
    unsigned fphase = 0;
    for (int d = 2; d >= 0; --d) {
        const int n = 1 << d;
        const f16* h_in = hLvl(H, d + 1);
        const float* c_in = cLvl(C, d + 1);
        f16* h_out = hLvl(H, d);
        float* c_out = cLvl(C, d);
        if (w == 0)
            tile_compute<12, 1>(emb, Bs, n, 0, n, l15, kq, j,
                                bi, bfv, bg, bo, h_in, c_in, h_out, c_out,
                                (d == 0) ? root_out : nullptr);
        if (d > 0) {
            ++fphase;
            __syncthreads();
            if (tid == 0) {
                __hip_atomic_fetch_add(&sync[FBARI], 1u,
                                       __ATOMIC_RELAXED, __HIP_MEMORY_SCOPE_AGENT);
                while (__hip_atomic_load(&sync[FBARI], __ATOMIC_RELAXED,
                                         __HIP_MEMORY_SCOPE_AGENT) < fphase * 8u)
                    __builtin_amdgcn_s_sleep(4);
                asm volatile("buffer_inv sc0" ::: "memory");
            }
            __syncthreads();
        }
    }
}

extern "C" void kernel_launch(void* const* d_in, const int* in_sizes, int n_in,
                              void* d_out, int out_size, void* d_ws, size_t ws_size,
                              hipStream_t stream) {
    const float* emb  = (const float*)d_in[0];
    const float* W_ih = (const float*)d_in[1];
    const float* W_hh = (const float*)d_in[2];
    const float* b_ih = (const float*)d_in[3];
    const float* b_hh = (const float*)d_in[4];

    char* wsb = (char*)d_ws;
    f16*   Bp    = (f16*)wsb;                      // 393216 B
    float* biasP = (float*)(wsb + 393216);         // 2048 B
    unsigned* syncp = (unsigned*)(wsb + 397312);   // 4096 B reserved
    char* H = wsb + 1048576;                       // 64 MiB per-level h
    char* C = wsb + 1048576 + 67108864;            // 64 MiB per-level c
    if (ws_size < 1048576 + 2 * 67108864) return;

    pack_weights<<<768, 256, 0, stream>>>(W_ih, W_hh, b_ih, b_hh, Bp, biasP);
    mega<<<768, 256, 0, stream>>>(emb, Bp, biasP, H, C, (float*)d_out, syncp);
}